// Round 7
// baseline (257.622 us; speedup 1.0000x reference)
//
#include <hip/hip_runtime.h>
#include <hip/hip_bf16.h>
#include <cstdint>
#include <cstddef>

#define DIMD 1024
#define LSEQ 4096
#define BATCH 4
#define MTOT (BATCH*LSEQ)          // 16384
#define NCHUNK 64
#define CHUNKLEN 64                // NCHUNK*CHUNKLEN == LSEQ
#define GATE_ELEMS ((size_t)MTOT*DIMD)
#define NTILE_K 16                 // 1024 / 64

typedef __bf16 bf16x8 __attribute__((ext_vector_type(8)));
typedef float f32x4 __attribute__((ext_vector_type(4)));

__device__ __forceinline__ unsigned short f2bf(float f) {
    union { float f; uint32_t u; } v; v.f = f;
    uint32_t r = v.u + 0x7fffu + ((v.u >> 16) & 1u);   // RNE
    return (unsigned short)(r >> 16);
}
__device__ __forceinline__ float bits2f(unsigned short b) {
    union { uint32_t u; float f; } v; v.u = ((uint32_t)b) << 16; return v.f;
}
__device__ __forceinline__ float gld(const float* p, size_t o) { return p[o]; }
__device__ __forceinline__ float gld(const unsigned short* p, size_t o) { return bits2f(p[o]); }
__device__ __forceinline__ void  gst(float* p, size_t o, float v) { p[o] = v; }
__device__ __forceinline__ void  gst(unsigned short* p, size_t o, float v) { p[o] = f2bf(v); }

__device__ __forceinline__ float fsig(float x) {
    return __builtin_amdgcn_rcpf(1.f + __expf(-x));
}

// ---------------- cast fp32 -> bf16 (vectorized 8/thread) ----------------
__global__ void cast_f32_to_bf16(const float* __restrict__ src,
                                 unsigned short* __restrict__ dst, int n) {
    int i = (blockIdx.x * blockDim.x + threadIdx.x) * 8;
    if (i >= n) return;
    float4 a = *(const float4*)(src + i);
    float4 b = *(const float4*)(src + i + 4);
    uint4 o;
    o.x = (uint32_t)f2bf(a.x) | ((uint32_t)f2bf(a.y) << 16);
    o.y = (uint32_t)f2bf(a.z) | ((uint32_t)f2bf(a.w) << 16);
    o.z = (uint32_t)f2bf(b.x) | ((uint32_t)f2bf(b.y) << 16);
    o.w = (uint32_t)f2bf(b.z) | ((uint32_t)f2bf(b.w) << 16);
    *(uint4*)(dst + i) = o;
}

// ---------------- 256x256-tile 8-wave fine-phase pipelined 4-gate GEMM ----------------
// Depth-2 prefetch (stage t+2 during tile t's P3), vmcnt(8) once per tile.
// CRITICAL (R5/R6 bug): vmcnt is PER-WAVE — it proves only this wave's
// global_load_lds landed; tile data is written by ALL waves' loads. So the
// loop-top sequence MUST be: vmcnt -> s_barrier -> ds_reads. The barrier turns
// "each wave verified its own loads" into "all tile-t loads landed".
// 4 fine phases/tile, quadrant order (00)(01)(10)(11); reads 12/4/8/0 + stage.
// sched_barrier(0) pins keep each phase region intact (s_barrier is IntrNoMem).
template <typename T>
__global__ __launch_bounds__(512, 1) void gemm_gates8(
    const unsigned short* __restrict__ Xb,    // [16384][1024] bf16 bits
    const unsigned short* __restrict__ Wcat,  // [4096][1024]  bf16 bits
    const float* __restrict__ bf_, const float* __restrict__ bi_,
    const float* __restrict__ big_, const float* __restrict__ bog_,
    T* __restrict__ G)                        // [4][16384][1024]
{
    __shared__ __align__(16) char lds[131072];
    char* ldsA = lds;            // 2 bufs x (2 M-halves x 16KB)
    char* ldsB = lds + 65536;

    const int tid = threadIdx.x;
    const int wave = tid >> 6, lane = tid & 63;
    const int wm = wave >> 2, wn = wave & 3;       // 2 x 4 wave grid
    const int l15 = lane & 15, l4 = lane >> 4;
    const int m7 = l15 & 7;

    // T1: bijective XCD swizzle (1024 blocks), nt-slab per XCD
    const int wg = blockIdx.x;
    const int swz = (wg & 7) * 128 + (wg >> 3);
    const int mt = swz & 63, nt = swz >> 6;
    const int m0 = mt * 256, n0 = nt * 256;

    // ---- hoisted swizzled LDS read bases (buf toggles via bufOff) ----
    const char* Abase0 = ldsA + wm * 16384 + l15 * 128 + (((0 + l4) ^ m7) << 4);
    const char* Abase1 = ldsA + wm * 16384 + l15 * 128 + (((4 + l4) ^ m7) << 4);
    const char* Bbase0 = ldsB + (wn >> 1) * 16384 + ((wn & 1) * 64 + l15) * 128 + (((0 + l4) ^ m7) << 4);
    const char* Bbase1 = ldsB + (wn >> 1) * 16384 + ((wn & 1) * 64 + l15) * 128 + (((4 + l4) ^ m7) << 4);

    // ---- one-time stage lambda (prologue) ----
    auto stage = [&](const unsigned short* src, int rowbase, int k0, char* region, int buf) {
#pragma unroll
        for (int half = 0; half < 2; ++half) {
            char* slot = region + (buf * 2 + half) * 16384;
#pragma unroll
            for (int j = 0; j < 2; ++j) {
                int r = (tid >> 3) + j * 64;
                int scol = (tid & 7) ^ (r & 7);
                const unsigned short* g = src + (size_t)(rowbase + half * 128 + r) * DIMD + k0 + scol * 8;
                __builtin_amdgcn_global_load_lds(
                    (const __attribute__((address_space(1))) uint32_t*)g,
                    (__attribute__((address_space(3))) uint32_t*)(slot + (wave << 10) + (j << 13)),
                    16, 0, 0);
            }
        }
    };

    // ---- running stage source pointers (tile 2 onward) ----
    const unsigned short* pA[2][2];
    const unsigned short* pB[2][2];
#pragma unroll
    for (int half = 0; half < 2; ++half)
#pragma unroll
        for (int j = 0; j < 2; ++j) {
            int r = (tid >> 3) + j * 64;
            int scol = (tid & 7) ^ (r & 7);
            pA[half][j] = Xb + (size_t)(m0 + half * 128 + r) * DIMD + 128 + scol * 8;
            pB[half][j] = Wcat + (size_t)(n0 + half * 128 + r) * DIMD + 128 + scol * 8;
        }

    f32x4 acc[8][4];
#pragma unroll
    for (int m = 0; m < 8; ++m)
#pragma unroll
        for (int n = 0; n < 4; ++n) acc[m][n] = (f32x4)0.f;

    // prologue: stage tiles 0 and 1
    stage(Xb, m0, 0, ldsA, 0);   stage(Wcat, n0, 0, ldsB, 0);
    stage(Xb, m0, 64, ldsA, 1);  stage(Wcat, n0, 64, ldsB, 1);

    int bufOff = 0;
#pragma unroll 1
    for (int t = 0; t < NTILE_K; ++t) {
        if (t == NTILE_K - 1) asm volatile("s_waitcnt vmcnt(0)" ::: "memory");
        else                  asm volatile("s_waitcnt vmcnt(8)" ::: "memory");
        // tile-ready barrier: after it, ALL waves' tile-t loads have landed.
        __builtin_amdgcn_s_barrier();
        __builtin_amdgcn_sched_barrier(0);

        bf16x8 av0[4][2], av1[4][2], bv0[2][2], bv1[2][2];

        // ---------- P0: reads av0 (8) + bv0 (4); MFMA (mq0,nq0) ----------
#pragma unroll
        for (int i = 0; i < 4; ++i) {
            av0[i][0] = *(const bf16x8*)(Abase0 + bufOff + i * 2048);
            av0[i][1] = *(const bf16x8*)(Abase1 + bufOff + i * 2048);
        }
#pragma unroll
        for (int i2 = 0; i2 < 2; ++i2) {
            bv0[i2][0] = *(const bf16x8*)(Bbase0 + bufOff + i2 * 2048);
            bv0[i2][1] = *(const bf16x8*)(Bbase1 + bufOff + i2 * 2048);
        }
        __builtin_amdgcn_sched_barrier(0);
        __builtin_amdgcn_s_barrier();
        __builtin_amdgcn_s_setprio(1);
#pragma unroll
        for (int kk = 0; kk < 2; ++kk)
#pragma unroll
            for (int i = 0; i < 4; ++i)
#pragma unroll
                for (int i2 = 0; i2 < 2; ++i2)
                    acc[i][i2] = __builtin_amdgcn_mfma_f32_16x16x32_bf16(av0[i][kk], bv0[i2][kk], acc[i][i2], 0, 0, 0);
        __builtin_amdgcn_s_setprio(0);
        __builtin_amdgcn_s_barrier();
        __builtin_amdgcn_sched_barrier(0);

        // ---------- P1: reads bv1 (4); MFMA (mq0,nq1) ----------
#pragma unroll
        for (int i2 = 0; i2 < 2; ++i2) {
            bv1[i2][0] = *(const bf16x8*)(Bbase0 + bufOff + (2 + i2) * 2048);
            bv1[i2][1] = *(const bf16x8*)(Bbase1 + bufOff + (2 + i2) * 2048);
        }
        __builtin_amdgcn_sched_barrier(0);
        __builtin_amdgcn_s_barrier();
        __builtin_amdgcn_s_setprio(1);
#pragma unroll
        for (int kk = 0; kk < 2; ++kk)
#pragma unroll
            for (int i = 0; i < 4; ++i)
#pragma unroll
                for (int i2 = 0; i2 < 2; ++i2)
                    acc[i][2 + i2] = __builtin_amdgcn_mfma_f32_16x16x32_bf16(av0[i][kk], bv1[i2][kk], acc[i][2 + i2], 0, 0, 0);
        __builtin_amdgcn_s_setprio(0);
        __builtin_amdgcn_s_barrier();
        __builtin_amdgcn_sched_barrier(0);

        // ---------- P2: reads av1 (8); MFMA (mq1,nq0) ----------
#pragma unroll
        for (int i = 0; i < 4; ++i) {
            av1[i][0] = *(const bf16x8*)(Abase0 + bufOff + (4 + i) * 2048);
            av1[i][1] = *(const bf16x8*)(Abase1 + bufOff + (4 + i) * 2048);
        }
        __builtin_amdgcn_sched_barrier(0);
        __builtin_amdgcn_s_barrier();
        __builtin_amdgcn_s_setprio(1);
#pragma unroll
        for (int kk = 0; kk < 2; ++kk)
#pragma unroll
            for (int i = 0; i < 4; ++i)
#pragma unroll
                for (int i2 = 0; i2 < 2; ++i2)
                    acc[4 + i][i2] = __builtin_amdgcn_mfma_f32_16x16x32_bf16(av1[i][kk], bv0[i2][kk], acc[4 + i][i2], 0, 0, 0);
        __builtin_amdgcn_s_setprio(0);
        __builtin_amdgcn_s_barrier();
        __builtin_amdgcn_sched_barrier(0);
        // ^ all waves' ds_reads of this buffer completed before this point
        //   (each wave's reads drained via lgkm dep before its P2 MFMA issued).

        // ---------- P3: stage t+2 (8 gloads); MFMA (mq1,nq1) ----------
        if (t + 2 < NTILE_K) {
#pragma unroll
            for (int half = 0; half < 2; ++half)
#pragma unroll
                for (int j = 0; j < 2; ++j) {
                    __builtin_amdgcn_global_load_lds(
                        (const __attribute__((address_space(1))) uint32_t*)pA[half][j],
                        (__attribute__((address_space(3))) uint32_t*)(ldsA + bufOff + half * 16384 + (wave << 10) + (j << 13)),
                        16, 0, 0);
                    pA[half][j] += 64;
                }
#pragma unroll
            for (int half = 0; half < 2; ++half)
#pragma unroll
                for (int j = 0; j < 2; ++j) {
                    __builtin_amdgcn_global_load_lds(
                        (const __attribute__((address_space(1))) uint32_t*)pB[half][j],
                        (__attribute__((address_space(3))) uint32_t*)(ldsB + bufOff + half * 16384 + (wave << 10) + (j << 13)),
                        16, 0, 0);
                    pB[half][j] += 64;
                }
        }
        __builtin_amdgcn_sched_barrier(0);
        __builtin_amdgcn_s_barrier();
        __builtin_amdgcn_s_setprio(1);
#pragma unroll
        for (int kk = 0; kk < 2; ++kk)
#pragma unroll
            for (int i = 0; i < 4; ++i)
#pragma unroll
                for (int i2 = 0; i2 < 2; ++i2)
                    acc[4 + i][2 + i2] = __builtin_amdgcn_mfma_f32_16x16x32_bf16(av1[i][kk], bv1[i2][kk], acc[4 + i][2 + i2], 0, 0, 0);
        __builtin_amdgcn_s_setprio(0);
        __builtin_amdgcn_s_barrier();
        __builtin_amdgcn_sched_barrier(0);

        bufOff ^= 32768;
    }

    // epilogue: bias + activation + store
    const int gate = n0 >> 10;
    const float* bias = (gate == 0) ? bf_ : (gate == 1) ? bi_ : (gate == 2) ? big_ : bog_;
    T* Gg = G + (size_t)gate * GATE_ELEMS;
    const int ebase = (n0 & 1023) + wn * 64;
    const int rowb0 = m0 + wm * 128;
    float bvv[4];
#pragma unroll
    for (int nf = 0; nf < 4; ++nf) bvv[nf] = bias[ebase + nf * 16 + l15];
#pragma unroll
    for (int mf = 0; mf < 8; ++mf) {
        int rowb = rowb0 + mf * 16 + l4 * 4;
#pragma unroll
        for (int r = 0; r < 4; ++r) {
            size_t rowoff = (size_t)(rowb + r) * DIMD;
#pragma unroll
            for (int nf = 0; nf < 4; ++nf) {
                float pre = acc[mf][nf][r] + bvv[nf];
                float v = (gate == 1) ? (2.f * fsig(2.f * pre) - 1.f) : fsig(pre);
                gst(Gg, rowoff + ebase + nf * 16 + l15, v);
            }
        }
    }
}

// ---------------- scan phase 1: per-chunk affine aggregates ----------------
template <typename T>
__global__ void scan_phase1(const T* __restrict__ F, const T* __restrict__ TI,
                            const T* __restrict__ SG,
                            float* __restrict__ Aagg, float* __restrict__ Bagg) {
    const int d = blockIdx.x * blockDim.x + threadIdx.x;  // 0..1023
    const int c = blockIdx.y, b = blockIdx.z;
    size_t base = ((size_t)b * LSEQ + (size_t)c * CHUNKLEN) * DIMD + d;
    float A = 1.f, Bv = 0.f;
#pragma unroll 8
    for (int t = 0; t < CHUNKLEN; ++t) {
        size_t off = base + (size_t)t * DIMD;
        float f = gld(F, off);
        float i = gld(TI, off) * gld(SG, off);
        A *= f;
        Bv = __builtin_fmaf(f, Bv, i);
    }
    size_t o = ((size_t)b * NCHUNK + c) * DIMD + d;
    Aagg[o] = A;
    Bagg[o] = Bv;
}

// ---------------- scan phase 2: sequential scan over chunk aggregates ----------------
__global__ void scan_phase2(const float* __restrict__ Aagg, const float* __restrict__ Bagg,
                            const float* __restrict__ hidden,
                            float* __restrict__ Hstart, float* __restrict__ out_h) {
    int idx = blockIdx.x * blockDim.x + threadIdx.x;  // 0..4095
    int b = idx >> 10, d = idx & 1023;
    float h = hidden[b * 1024 + d];
    for (int c = 0; c < NCHUNK; ++c) {
        size_t o = ((size_t)b * NCHUNK + c) * DIMD + d;
        Hstart[o] = h;
        h = __builtin_fmaf(Aagg[o], h, Bagg[o]);
    }
    out_h[b * 1024 + d] = h;
}

// ---------------- scan phase 3: replay chunk with prefix, write y ----------------
template <typename T>
__global__ void scan_phase3(const T* __restrict__ F, const T* __restrict__ TI,
                            const T* __restrict__ SG, const T* __restrict__ OG,
                            const float* __restrict__ Hstart, float* __restrict__ y) {
    const int d = blockIdx.x * blockDim.x + threadIdx.x;
    const int c = blockIdx.y, b = blockIdx.z;
    float h = Hstart[((size_t)b * NCHUNK + c) * DIMD + d];
    size_t base = ((size_t)b * LSEQ + (size_t)c * CHUNKLEN) * DIMD + d;
#pragma unroll 4
    for (int t = 0; t < CHUNKLEN; ++t) {
        size_t off = base + (size_t)t * DIMD;
        float f = gld(F, off);
        float i = gld(TI, off) * gld(SG, off);
        h = __builtin_fmaf(f, h, i);
        y[off] = tanhf(h) * gld(OG, off);
    }
}

// ---------------- launch ----------------
extern "C" void kernel_launch(void* const* d_in, const int* in_sizes, int n_in,
                              void* d_out, int out_size, void* d_ws, size_t ws_size,
                              hipStream_t stream) {
    const float* x      = (const float*)d_in[0];
    const float* hidden = (const float*)d_in[1];
    const float* Wf  = (const float*)d_in[2];
    const float* bf_ = (const float*)d_in[3];
    const float* Wi  = (const float*)d_in[4];
    const float* bi_ = (const float*)d_in[5];
    const float* Wig = (const float*)d_in[6];
    const float* big_= (const float*)d_in[7];
    const float* Wog = (const float*)d_in[8];
    const float* bog_= (const float*)d_in[9];

    char* ws = (char*)d_ws;
    unsigned short* Xb   = (unsigned short*)(ws);            // 33,554,432 B
    unsigned short* Wcat = (unsigned short*)(ws + 33554432); //  8,388,608 B
    // gates start at 41,943,040

    float* y     = (float*)d_out;                 // [4][4096][1024]
    float* out_h = y + GATE_ELEMS;                // [4][1024]

    // casts
    cast_f32_to_bf16<<<MTOT * DIMD / 8 / 256, 256, 0, stream>>>(x, Xb, MTOT * DIMD);
    cast_f32_to_bf16<<<DIMD * DIMD / 8 / 256, 256, 0, stream>>>(Wf,  Wcat + 0 * DIMD * DIMD, DIMD * DIMD);
    cast_f32_to_bf16<<<DIMD * DIMD / 8 / 256, 256, 0, stream>>>(Wi,  Wcat + 1 * DIMD * DIMD, DIMD * DIMD);
    cast_f32_to_bf16<<<DIMD * DIMD / 8 / 256, 256, 0, stream>>>(Wig, Wcat + 2 * DIMD * DIMD, DIMD * DIMD);
    cast_f32_to_bf16<<<DIMD * DIMD / 8 / 256, 256, 0, stream>>>(Wog, Wcat + 3 * DIMD * DIMD, DIMD * DIMD);

    const size_t FP32_WS_NEED = 33554432ull + 8388608ull + GATE_ELEMS * 4 * 4 + 3ull * 1048576ull;
    if (ws_size >= FP32_WS_NEED) {
        // -------- fp32-gate path --------
        float* G      = (float*)(ws + 41943040);
        float* Aagg   = (float*)(ws + 310378496);
        float* Bagg   = (float*)(ws + 311427072);
        float* Hstart = (float*)(ws + 312475648);
        gemm_gates8<float><<<dim3(MTOT / 256 * (4096 / 256)), 512, 0, stream>>>(
            Xb, Wcat, bf_, bi_, big_, bog_, G);
        const float* Fg  = G;
        const float* TIg = G + 1 * GATE_ELEMS;
        const float* SGg = G + 2 * GATE_ELEMS;
        const float* OGg = G + 3 * GATE_ELEMS;
        scan_phase1<float><<<dim3(DIMD / 256, NCHUNK, BATCH), 256, 0, stream>>>(Fg, TIg, SGg, Aagg, Bagg);
        scan_phase2<<<BATCH * DIMD / 256, 256, 0, stream>>>(Aagg, Bagg, hidden, Hstart, out_h);
        scan_phase3<float><<<dim3(DIMD / 256, NCHUNK, BATCH), 256, 0, stream>>>(Fg, TIg, SGg, OGg, Hstart, y);
    } else {
        // -------- bf16-gate path (ws need: 179,306,496 B = 171 MiB) --------
        unsigned short* G = (unsigned short*)(ws + 41943040);
        float* Aagg   = (float*)(ws + 176160768);
        float* Bagg   = (float*)(ws + 177209344);
        float* Hstart = (float*)(ws + 178257920);
        gemm_gates8<unsigned short><<<dim3(MTOT / 256 * (4096 / 256)), 512, 0, stream>>>(
            Xb, Wcat, bf_, bi_, big_, bog_, G);
        const unsigned short* Fg  = G;
        const unsigned short* TIg = G + 1 * GATE_ELEMS;
        const unsigned short* SGg = G + 2 * GATE_ELEMS;
        const unsigned short* OGg = G + 3 * GATE_ELEMS;
        scan_phase1<unsigned short><<<dim3(DIMD / 256, NCHUNK, BATCH), 256, 0, stream>>>(Fg, TIg, SGg, Aagg, Bagg);
        scan_phase2<<<BATCH * DIMD / 256, 256, 0, stream>>>(Aagg, Bagg, hidden, Hstart, out_h);
        scan_phase3<unsigned short><<<dim3(DIMD / 256, NCHUNK, BATCH), 256, 0, stream>>>(Fg, TIg, SGg, OGg, Hstart, y);
    }
}

// Round 8
// 256.690 us; speedup vs baseline: 1.0036x; 1.0036x over previous
//
#include <hip/hip_runtime.h>
#include <hip/hip_bf16.h>
#include <cstdint>
#include <cstddef>

#define DIMD 1024
#define LSEQ 4096
#define BATCH 4
#define MTOT (BATCH*LSEQ)          // 16384
#define NCHUNK 64
#define CHUNKLEN 64                // NCHUNK*CHUNKLEN == LSEQ
#define GATE_ELEMS ((size_t)MTOT*DIMD)
#define NTILE_K 16                 // 1024 / 64

typedef __bf16 bf16x8 __attribute__((ext_vector_type(8)));
typedef float f32x4 __attribute__((ext_vector_type(4)));

__device__ __forceinline__ unsigned short f2bf(float f) {
    union { float f; uint32_t u; } v; v.f = f;
    uint32_t r = v.u + 0x7fffu + ((v.u >> 16) & 1u);   // RNE
    return (unsigned short)(r >> 16);
}
__device__ __forceinline__ float bits2f(unsigned short b) {
    union { uint32_t u; float f; } v; v.u = ((uint32_t)b) << 16; return v.f;
}
__device__ __forceinline__ float gld(const float* p, size_t o) { return p[o]; }
__device__ __forceinline__ float gld(const unsigned short* p, size_t o) { return bits2f(p[o]); }
__device__ __forceinline__ void  gst(float* p, size_t o, float v) { p[o] = v; }
__device__ __forceinline__ void  gst(unsigned short* p, size_t o, float v) { p[o] = f2bf(v); }

__device__ __forceinline__ float fsig(float x) {
    return __builtin_amdgcn_rcpf(1.f + __expf(-x));
}

// ---------------- cast fp32 -> bf16 (vectorized 8/thread) ----------------
__global__ void cast_f32_to_bf16(const float* __restrict__ src,
                                 unsigned short* __restrict__ dst, int n) {
    int i = (blockIdx.x * blockDim.x + threadIdx.x) * 8;
    if (i >= n) return;
    float4 a = *(const float4*)(src + i);
    float4 b = *(const float4*)(src + i + 4);
    uint4 o;
    o.x = (uint32_t)f2bf(a.x) | ((uint32_t)f2bf(a.y) << 16);
    o.y = (uint32_t)f2bf(a.z) | ((uint32_t)f2bf(a.w) << 16);
    o.z = (uint32_t)f2bf(b.x) | ((uint32_t)f2bf(b.y) << 16);
    o.w = (uint32_t)f2bf(b.z) | ((uint32_t)f2bf(b.w) << 16);
    *(uint4*)(dst + i) = o;
}

// ---------------- 256x256-tile 8-wave fine-phase pipelined 4-gate GEMM ----------------
// Depth-2 prefetch (stage t+2 in P3), vmcnt(8) per tile.
// RAW rule (R5/R6 bug): vmcnt is PER-WAVE; the sequence must be
// vmcnt -> s_barrier -> ds_reads so "my loads landed" becomes "all loads landed".
// The asm volatile "memory" clobber on vmcnt is what stops ds_read hoisting.
// R8: removed the R7 sched_barrier(0) pins (m141: pins defeat the scheduler);
// merged the tile-ready barrier into P3's end barrier (8 barriers/tile).
template <typename T>
__global__ __launch_bounds__(512, 1) void gemm_gates8(
    const unsigned short* __restrict__ Xb,    // [16384][1024] bf16 bits
    const unsigned short* __restrict__ Wcat,  // [4096][1024]  bf16 bits
    const float* __restrict__ bf_, const float* __restrict__ bi_,
    const float* __restrict__ big_, const float* __restrict__ bog_,
    T* __restrict__ G)                        // [4][16384][1024]
{
    __shared__ __align__(16) char lds[131072];
    char* ldsA = lds;            // 2 bufs x (2 M-halves x 16KB)
    char* ldsB = lds + 65536;

    const int tid = threadIdx.x;
    const int wave = tid >> 6, lane = tid & 63;
    const int wm = wave >> 2, wn = wave & 3;       // 2 x 4 wave grid
    const int l15 = lane & 15, l4 = lane >> 4;
    const int m7 = l15 & 7;

    // T1: bijective XCD swizzle (1024 blocks), nt-slab per XCD
    const int wg = blockIdx.x;
    const int swz = (wg & 7) * 128 + (wg >> 3);
    const int mt = swz & 63, nt = swz >> 6;
    const int m0 = mt * 256, n0 = nt * 256;

    // ---- hoisted swizzled LDS read bases (buf toggles via bufOff) ----
    const char* Abase0 = ldsA + wm * 16384 + l15 * 128 + (((0 + l4) ^ m7) << 4);
    const char* Abase1 = ldsA + wm * 16384 + l15 * 128 + (((4 + l4) ^ m7) << 4);
    const char* Bbase0 = ldsB + (wn >> 1) * 16384 + ((wn & 1) * 64 + l15) * 128 + (((0 + l4) ^ m7) << 4);
    const char* Bbase1 = ldsB + (wn >> 1) * 16384 + ((wn & 1) * 64 + l15) * 128 + (((4 + l4) ^ m7) << 4);

    // ---- one-time stage lambda (prologue) ----
    auto stage = [&](const unsigned short* src, int rowbase, int k0, char* region, int buf) {
#pragma unroll
        for (int half = 0; half < 2; ++half) {
            char* slot = region + (buf * 2 + half) * 16384;
#pragma unroll
            for (int j = 0; j < 2; ++j) {
                int r = (tid >> 3) + j * 64;
                int scol = (tid & 7) ^ (r & 7);
                const unsigned short* g = src + (size_t)(rowbase + half * 128 + r) * DIMD + k0 + scol * 8;
                __builtin_amdgcn_global_load_lds(
                    (const __attribute__((address_space(1))) uint32_t*)g,
                    (__attribute__((address_space(3))) uint32_t*)(slot + (wave << 10) + (j << 13)),
                    16, 0, 0);
            }
        }
    };

    // ---- running stage source pointers (tile 2 onward) ----
    const unsigned short* pA[2][2];
    const unsigned short* pB[2][2];
#pragma unroll
    for (int half = 0; half < 2; ++half)
#pragma unroll
        for (int j = 0; j < 2; ++j) {
            int r = (tid >> 3) + j * 64;
            int scol = (tid & 7) ^ (r & 7);
            pA[half][j] = Xb + (size_t)(m0 + half * 128 + r) * DIMD + 128 + scol * 8;
            pB[half][j] = Wcat + (size_t)(n0 + half * 128 + r) * DIMD + 128 + scol * 8;
        }

    f32x4 acc[8][4];
#pragma unroll
    for (int m = 0; m < 8; ++m)
#pragma unroll
        for (int n = 0; n < 4; ++n) acc[m][n] = (f32x4)0.f;

    // prologue: stage tiles 0 and 1; tile-0 ready gate
    stage(Xb, m0, 0, ldsA, 0);   stage(Wcat, n0, 0, ldsB, 0);
    stage(Xb, m0, 64, ldsA, 1);  stage(Wcat, n0, 64, ldsB, 1);
    asm volatile("s_waitcnt vmcnt(8)" ::: "memory");
    __builtin_amdgcn_s_barrier();

    int bufOff = 0;
#pragma unroll 1
    for (int t = 0; t < NTILE_K; ++t) {
        bf16x8 av0[4][2], av1[4][2], bv0[2][2], bv1[2][2];

        // ---------- P0: reads av0 (8) + bv0 (4); MFMA (mq0,nq0) ----------
#pragma unroll
        for (int i = 0; i < 4; ++i) {
            av0[i][0] = *(const bf16x8*)(Abase0 + bufOff + i * 2048);
            av0[i][1] = *(const bf16x8*)(Abase1 + bufOff + i * 2048);
        }
#pragma unroll
        for (int i2 = 0; i2 < 2; ++i2) {
            bv0[i2][0] = *(const bf16x8*)(Bbase0 + bufOff + i2 * 2048);
            bv0[i2][1] = *(const bf16x8*)(Bbase1 + bufOff + i2 * 2048);
        }
        __builtin_amdgcn_s_barrier();
        __builtin_amdgcn_s_setprio(1);
#pragma unroll
        for (int kk = 0; kk < 2; ++kk)
#pragma unroll
            for (int i = 0; i < 4; ++i)
#pragma unroll
                for (int i2 = 0; i2 < 2; ++i2)
                    acc[i][i2] = __builtin_amdgcn_mfma_f32_16x16x32_bf16(av0[i][kk], bv0[i2][kk], acc[i][i2], 0, 0, 0);
        __builtin_amdgcn_s_setprio(0);
        __builtin_amdgcn_s_barrier();

        // ---------- P1: reads bv1 (4); MFMA (mq0,nq1) ----------
#pragma unroll
        for (int i2 = 0; i2 < 2; ++i2) {
            bv1[i2][0] = *(const bf16x8*)(Bbase0 + bufOff + (2 + i2) * 2048);
            bv1[i2][1] = *(const bf16x8*)(Bbase1 + bufOff + (2 + i2) * 2048);
        }
        __builtin_amdgcn_s_barrier();
        __builtin_amdgcn_s_setprio(1);
#pragma unroll
        for (int kk = 0; kk < 2; ++kk)
#pragma unroll
            for (int i = 0; i < 4; ++i)
#pragma unroll
                for (int i2 = 0; i2 < 2; ++i2)
                    acc[i][2 + i2] = __builtin_amdgcn_mfma_f32_16x16x32_bf16(av0[i][kk], bv1[i2][kk], acc[i][2 + i2], 0, 0, 0);
        __builtin_amdgcn_s_setprio(0);
        __builtin_amdgcn_s_barrier();

        // ---------- P2: reads av1 (8); MFMA (mq1,nq0) ----------
#pragma unroll
        for (int i = 0; i < 4; ++i) {
            av1[i][0] = *(const bf16x8*)(Abase0 + bufOff + (4 + i) * 2048);
            av1[i][1] = *(const bf16x8*)(Abase1 + bufOff + (4 + i) * 2048);
        }
        __builtin_amdgcn_s_barrier();
        __builtin_amdgcn_s_setprio(1);
#pragma unroll
        for (int kk = 0; kk < 2; ++kk)
#pragma unroll
            for (int i = 0; i < 4; ++i)
#pragma unroll
                for (int i2 = 0; i2 < 2; ++i2)
                    acc[4 + i][i2] = __builtin_amdgcn_mfma_f32_16x16x32_bf16(av1[i][kk], bv0[i2][kk], acc[4 + i][i2], 0, 0, 0);
        __builtin_amdgcn_s_setprio(0);
        __builtin_amdgcn_s_barrier();
        // after this barrier, ALL waves' ds_reads of buffer (t&1) are complete.

        // ---------- P3: stage t+2 (8 gloads); MFMA (mq1,nq1); merged end/ready barrier ----------
        __builtin_amdgcn_sched_barrier(0);   // keep the stage below the WAR barrier above
        if (t + 2 < NTILE_K) {
#pragma unroll
            for (int half = 0; half < 2; ++half)
#pragma unroll
                for (int j = 0; j < 2; ++j) {
                    __builtin_amdgcn_global_load_lds(
                        (const __attribute__((address_space(1))) uint32_t*)pA[half][j],
                        (__attribute__((address_space(3))) uint32_t*)(ldsA + bufOff + half * 16384 + (wave << 10) + (j << 13)),
                        16, 0, 0);
                    pA[half][j] += 64;
                }
#pragma unroll
            for (int half = 0; half < 2; ++half)
#pragma unroll
                for (int j = 0; j < 2; ++j) {
                    __builtin_amdgcn_global_load_lds(
                        (const __attribute__((address_space(1))) uint32_t*)pB[half][j],
                        (__attribute__((address_space(3))) uint32_t*)(ldsB + bufOff + half * 16384 + (wave << 10) + (j << 13)),
                        16, 0, 0);
                    pB[half][j] += 64;
                }
        }
        __builtin_amdgcn_s_barrier();
        __builtin_amdgcn_s_setprio(1);
#pragma unroll
        for (int kk = 0; kk < 2; ++kk)
#pragma unroll
            for (int i = 0; i < 4; ++i)
#pragma unroll
                for (int i2 = 0; i2 < 2; ++i2)
                    acc[4 + i][2 + i2] = __builtin_amdgcn_mfma_f32_16x16x32_bf16(av1[i][kk], bv1[i2][kk], acc[4 + i][2 + i2], 0, 0, 0);
        __builtin_amdgcn_s_setprio(0);

        // end of tile t: make tile t+1 ready for all waves (merged barrier).
        if (t + 1 < NTILE_K) {
            if (t + 2 < NTILE_K) asm volatile("s_waitcnt vmcnt(8)" ::: "memory");
            else                 asm volatile("s_waitcnt vmcnt(0)" ::: "memory");
            __builtin_amdgcn_s_barrier();
        }

        bufOff ^= 32768;
    }

    // epilogue: bias + activation + store
    const int gate = n0 >> 10;
    const float* bias = (gate == 0) ? bf_ : (gate == 1) ? bi_ : (gate == 2) ? big_ : bog_;
    T* Gg = G + (size_t)gate * GATE_ELEMS;
    const int ebase = (n0 & 1023) + wn * 64;
    const int rowb0 = m0 + wm * 128;
    float bvv[4];
#pragma unroll
    for (int nf = 0; nf < 4; ++nf) bvv[nf] = bias[ebase + nf * 16 + l15];
#pragma unroll
    for (int mf = 0; mf < 8; ++mf) {
        int rowb = rowb0 + mf * 16 + l4 * 4;
#pragma unroll
        for (int r = 0; r < 4; ++r) {
            size_t rowoff = (size_t)(rowb + r) * DIMD;
#pragma unroll
            for (int nf = 0; nf < 4; ++nf) {
                float pre = acc[mf][nf][r] + bvv[nf];
                float v = (gate == 1) ? (2.f * fsig(2.f * pre) - 1.f) : fsig(pre);
                gst(Gg, rowoff + ebase + nf * 16 + l15, v);
            }
        }
    }
}

// ---------------- scan phase 1: per-chunk affine aggregates ----------------
template <typename T>
__global__ void scan_phase1(const T* __restrict__ F, const T* __restrict__ TI,
                            const T* __restrict__ SG,
                            float* __restrict__ Aagg, float* __restrict__ Bagg) {
    const int d = blockIdx.x * blockDim.x + threadIdx.x;  // 0..1023
    const int c = blockIdx.y, b = blockIdx.z;
    size_t base = ((size_t)b * LSEQ + (size_t)c * CHUNKLEN) * DIMD + d;
    float A = 1.f, Bv = 0.f;
#pragma unroll 8
    for (int t = 0; t < CHUNKLEN; ++t) {
        size_t off = base + (size_t)t * DIMD;
        float f = gld(F, off);
        float i = gld(TI, off) * gld(SG, off);
        A *= f;
        Bv = __builtin_fmaf(f, Bv, i);
    }
    size_t o = ((size_t)b * NCHUNK + c) * DIMD + d;
    Aagg[o] = A;
    Bagg[o] = Bv;
}

// ---------------- scan phase 2: sequential scan over chunk aggregates ----------------
__global__ void scan_phase2(const float* __restrict__ Aagg, const float* __restrict__ Bagg,
                            const float* __restrict__ hidden,
                            float* __restrict__ Hstart, float* __restrict__ out_h) {
    int idx = blockIdx.x * blockDim.x + threadIdx.x;  // 0..4095
    int b = idx >> 10, d = idx & 1023;
    float h = hidden[b * 1024 + d];
    for (int c = 0; c < NCHUNK; ++c) {
        size_t o = ((size_t)b * NCHUNK + c) * DIMD + d;
        Hstart[o] = h;
        h = __builtin_fmaf(Aagg[o], h, Bagg[o]);
    }
    out_h[b * 1024 + d] = h;
}

// ---------------- scan phase 3: replay chunk with prefix, write y ----------------
template <typename T>
__global__ void scan_phase3(const T* __restrict__ F, const T* __restrict__ TI,
                            const T* __restrict__ SG, const T* __restrict__ OG,
                            const float* __restrict__ Hstart, float* __restrict__ y) {
    const int d = blockIdx.x * blockDim.x + threadIdx.x;
    const int c = blockIdx.y, b = blockIdx.z;
    float h = Hstart[((size_t)b * NCHUNK + c) * DIMD + d];
    size_t base = ((size_t)b * LSEQ + (size_t)c * CHUNKLEN) * DIMD + d;
#pragma unroll 4
    for (int t = 0; t < CHUNKLEN; ++t) {
        size_t off = base + (size_t)t * DIMD;
        float f = gld(F, off);
        float i = gld(TI, off) * gld(SG, off);
        h = __builtin_fmaf(f, h, i);
        y[off] = tanhf(h) * gld(OG, off);
    }
}

// ---------------- launch ----------------
extern "C" void kernel_launch(void* const* d_in, const int* in_sizes, int n_in,
                              void* d_out, int out_size, void* d_ws, size_t ws_size,
                              hipStream_t stream) {
    const float* x      = (const float*)d_in[0];
    const float* hidden = (const float*)d_in[1];
    const float* Wf  = (const float*)d_in[2];
    const float* bf_ = (const float*)d_in[3];
    const float* Wi  = (const float*)d_in[4];
    const float* bi_ = (const float*)d_in[5];
    const float* Wig = (const float*)d_in[6];
    const float* big_= (const float*)d_in[7];
    const float* Wog = (const float*)d_in[8];
    const float* bog_= (const float*)d_in[9];

    char* ws = (char*)d_ws;
    unsigned short* Xb   = (unsigned short*)(ws);            // 33,554,432 B
    unsigned short* Wcat = (unsigned short*)(ws + 33554432); //  8,388,608 B
    // gates start at 41,943,040

    float* y     = (float*)d_out;                 // [4][4096][1024]
    float* out_h = y + GATE_ELEMS;                // [4][1024]

    // casts
    cast_f32_to_bf16<<<MTOT * DIMD / 8 / 256, 256, 0, stream>>>(x, Xb, MTOT * DIMD);
    cast_f32_to_bf16<<<DIMD * DIMD / 8 / 256, 256, 0, stream>>>(Wf,  Wcat + 0 * DIMD * DIMD, DIMD * DIMD);
    cast_f32_to_bf16<<<DIMD * DIMD / 8 / 256, 256, 0, stream>>>(Wi,  Wcat + 1 * DIMD * DIMD, DIMD * DIMD);
    cast_f32_to_bf16<<<DIMD * DIMD / 8 / 256, 256, 0, stream>>>(Wig, Wcat + 2 * DIMD * DIMD, DIMD * DIMD);
    cast_f32_to_bf16<<<DIMD * DIMD / 8 / 256, 256, 0, stream>>>(Wog, Wcat + 3 * DIMD * DIMD, DIMD * DIMD);

    const size_t FP32_WS_NEED = 33554432ull + 8388608ull + GATE_ELEMS * 4 * 4 + 3ull * 1048576ull;
    if (ws_size >= FP32_WS_NEED) {
        // -------- fp32-gate path --------
        float* G      = (float*)(ws + 41943040);
        float* Aagg   = (float*)(ws + 310378496);
        float* Bagg   = (float*)(ws + 311427072);
        float* Hstart = (float*)(ws + 312475648);
        gemm_gates8<float><<<dim3(MTOT / 256 * (4096 / 256)), 512, 0, stream>>>(
            Xb, Wcat, bf_, bi_, big_, bog_, G);
        const float* Fg  = G;
        const float* TIg = G + 1 * GATE_ELEMS;
        const float* SGg = G + 2 * GATE_ELEMS;
        const float* OGg = G + 3 * GATE_ELEMS;
        scan_phase1<float><<<dim3(DIMD / 256, NCHUNK, BATCH), 256, 0, stream>>>(Fg, TIg, SGg, Aagg, Bagg);
        scan_phase2<<<BATCH * DIMD / 256, 256, 0, stream>>>(Aagg, Bagg, hidden, Hstart, out_h);
        scan_phase3<float><<<dim3(DIMD / 256, NCHUNK, BATCH), 256, 0, stream>>>(Fg, TIg, SGg, OGg, Hstart, y);
    } else {
        // -------- bf16-gate path (ws need: 179,306,496 B = 171 MiB) --------
        unsigned short* G = (unsigned short*)(ws + 41943040);
        float* Aagg   = (float*)(ws + 176160768);
        float* Bagg   = (float*)(ws + 177209344);
        float* Hstart = (float*)(ws + 178257920);
        gemm_gates8<unsigned short><<<dim3(MTOT / 256 * (4096 / 256)), 512, 0, stream>>>(
            Xb, Wcat, bf_, bi_, big_, bog_, G);
        const unsigned short* Fg  = G;
        const unsigned short* TIg = G + 1 * GATE_ELEMS;
        const unsigned short* SGg = G + 2 * GATE_ELEMS;
        const unsigned short* OGg = G + 3 * GATE_ELEMS;
        scan_phase1<unsigned short><<<dim3(DIMD / 256, NCHUNK, BATCH), 256, 0, stream>>>(Fg, TIg, SGg, Aagg, Bagg);
        scan_phase2<<<BATCH * DIMD / 256, 256, 0, stream>>>(Aagg, Bagg, hidden, Hstart, out_h);
        scan_phase3<unsigned short><<<dim3(DIMD / 256, NCHUNK, BATCH), 256, 0, stream>>>(Fg, TIg, SGg, OGg, Hstart, y);
    }
}

// Round 9
// 250.538 us; speedup vs baseline: 1.0283x; 1.0246x over previous
//
#include <hip/hip_runtime.h>
#include <hip/hip_bf16.h>
#include <cstdint>
#include <cstddef>

#define DIMD 1024
#define LSEQ 4096
#define BATCH 4
#define MTOT (BATCH*LSEQ)          // 16384
#define NCHUNK 64
#define CHUNKLEN 64                // NCHUNK*CHUNKLEN == LSEQ
#define GATE_ELEMS ((size_t)MTOT*DIMD)
#define NTILE_K 32                 // 1024 / 32  (BK=32)

typedef __bf16 bf16x8 __attribute__((ext_vector_type(8)));
typedef float f32x4 __attribute__((ext_vector_type(4)));

__device__ __forceinline__ unsigned short f2bf(float f) {
    union { float f; uint32_t u; } v; v.f = f;
    uint32_t r = v.u + 0x7fffu + ((v.u >> 16) & 1u);   // RNE
    return (unsigned short)(r >> 16);
}
__device__ __forceinline__ float bits2f(unsigned short b) {
    union { uint32_t u; float f; } v; v.u = ((uint32_t)b) << 16; return v.f;
}
__device__ __forceinline__ float gld(const float* p, size_t o) { return p[o]; }
__device__ __forceinline__ float gld(const unsigned short* p, size_t o) { return bits2f(p[o]); }
__device__ __forceinline__ void  gst(float* p, size_t o, float v) { p[o] = v; }
__device__ __forceinline__ void  gst(unsigned short* p, size_t o, float v) { p[o] = f2bf(v); }

__device__ __forceinline__ float fsig(float x) {
    return __builtin_amdgcn_rcpf(1.f + __expf(-x));
}

// ---------------- cast fp32 -> bf16 (vectorized 8/thread) ----------------
__global__ void cast_f32_to_bf16(const float* __restrict__ src,
                                 unsigned short* __restrict__ dst, int n) {
    int i = (blockIdx.x * blockDim.x + threadIdx.x) * 8;
    if (i >= n) return;
    float4 a = *(const float4*)(src + i);
    float4 b = *(const float4*)(src + i + 4);
    uint4 o;
    o.x = (uint32_t)f2bf(a.x) | ((uint32_t)f2bf(a.y) << 16);
    o.y = (uint32_t)f2bf(a.z) | ((uint32_t)f2bf(a.w) << 16);
    o.z = (uint32_t)f2bf(b.x) | ((uint32_t)f2bf(b.y) << 16);
    o.w = (uint32_t)f2bf(b.z) | ((uint32_t)f2bf(b.w) << 16);
    *(uint4*)(dst + i) = o;
}

// ---------------- 128x256-tile, BK=32, 3-buffer, 2 blocks/CU 4-gate GEMM ----------------
// Per-wave 64x64 (acc=64 VGPR) -> launch_bounds(512,4) for 2 resident blocks
// (the m114 inter-block overlap mechanism). 3 LDS buffers (72 KiB): stage(t+2)
// has no WAR hazard with reads(t) -> issued right after the tile-top barrier.
// Sync per tile: vmcnt(asm,"memory") -> s_barrier -> sched_barrier(0) -> stage|reads|MFMA.
// (vmcnt is PER-WAVE; the barrier makes "my loads landed" into "all loads landed".)
template <typename T>
__global__ __launch_bounds__(512, 4) void gemm_gates_s(
    const unsigned short* __restrict__ Xb,    // [16384][1024] bf16 bits
    const unsigned short* __restrict__ Wcat,  // [4096][1024]  bf16 bits
    const float* __restrict__ bf_, const float* __restrict__ bi_,
    const float* __restrict__ big_, const float* __restrict__ bog_,
    T* __restrict__ G)                        // [4][16384][1024]
{
    __shared__ __align__(16) char lds[73728];   // A: 3x8KB @0 ; B: 3x16KB @24576
    char* ldsA = lds;
    char* ldsB = lds + 24576;

    const int tid = threadIdx.x;
    const int wave = tid >> 6, lane = tid & 63;
    const int wm = wave >> 2, wn = wave & 3;       // 2 x 4 wave grid
    const int l15 = lane & 15, l4 = lane >> 4;

    // T1: bijective XCD swizzle (2048 blocks, %8==0), 2 nt-slabs per XCD
    const int wg = blockIdx.x;
    const int swz = (wg & 7) * 256 + (wg >> 3);
    const int mt = swz & 127, nt = swz >> 7;
    const int m0 = mt * 128, n0 = nt * 256;

    // ---- swizzled LDS read bases (row=64B, col-group XOR (row&3)) ----
    const int rsw = (l4 ^ (l15 & 3)) << 4;
    const char* ArdBase = ldsA + (wm * 64 + l15) * 64 + rsw;   // + m*1024 + offA
    const char* BrdBase = ldsB + (wn * 64 + l15) * 64 + rsw;   // + n*1024 + offB

    // ---- per-thread stage source bases (inverse swizzle on global col) ----
    const int srow = tid >> 2;                      // 0..127
    const int scg  = ((tid & 3) ^ (srow & 3)) * 8;  // col-group elem offset
    const unsigned short* pAsrc  = Xb   + (size_t)(m0 + srow) * DIMD + scg;
    const unsigned short* pBsrc0 = Wcat + (size_t)(n0 + srow) * DIMD + scg;
    const unsigned short* pBsrc1 = Wcat + (size_t)(n0 + 128 + srow) * DIMD + scg;

    auto stage3 = [&](int k0, int offA, int offB) {
        __builtin_amdgcn_global_load_lds(
            (const __attribute__((address_space(1))) uint32_t*)(pAsrc + k0),
            (__attribute__((address_space(3))) uint32_t*)(ldsA + offA + (wave << 10)), 16, 0, 0);
        __builtin_amdgcn_global_load_lds(
            (const __attribute__((address_space(1))) uint32_t*)(pBsrc0 + k0),
            (__attribute__((address_space(3))) uint32_t*)(ldsB + offB + (wave << 10)), 16, 0, 0);
        __builtin_amdgcn_global_load_lds(
            (const __attribute__((address_space(1))) uint32_t*)(pBsrc1 + k0),
            (__attribute__((address_space(3))) uint32_t*)(ldsB + offB + 8192 + (wave << 10)), 16, 0, 0);
    };

    f32x4 acc[4][4];
#pragma unroll
    for (int m = 0; m < 4; ++m)
#pragma unroll
        for (int n = 0; n < 4; ++n) acc[m][n] = (f32x4)0.f;

    // prologue: stage tiles 0 and 1
    stage3(0, 0, 0);
    stage3(32, 8192, 16384);

    int offA0 = 0, offA1 = 8192, offA2 = 16384;        // read / next / stage slots
    int offB0 = 0, offB1 = 16384, offB2 = 32768;       // (relative to ldsB)
#pragma unroll 1
    for (int t = 0; t < NTILE_K; ++t) {
        if (t <= NTILE_K - 2) asm volatile("s_waitcnt vmcnt(3)" ::: "memory");
        else                  asm volatile("s_waitcnt vmcnt(0)" ::: "memory");
        __builtin_amdgcn_s_barrier();          // all waves' tile-t loads landed
        __builtin_amdgcn_sched_barrier(0);     // no read/stage hoist above barrier

        if (t + 2 < NTILE_K) stage3((t + 2) * 32, offA2, offB2);

        bf16x8 bv[4], avl[2], avh[2];
#pragma unroll
        for (int n = 0; n < 4; ++n)
            bv[n] = *(const bf16x8*)(BrdBase + offB0 + n * 1024);
        avl[0] = *(const bf16x8*)(ArdBase + offA0);
        avl[1] = *(const bf16x8*)(ArdBase + offA0 + 1024);

        __builtin_amdgcn_s_setprio(1);
#pragma unroll
        for (int m = 0; m < 2; ++m)
#pragma unroll
            for (int n = 0; n < 4; ++n)
                acc[m][n] = __builtin_amdgcn_mfma_f32_16x16x32_bf16(avl[m], bv[n], acc[m][n], 0, 0, 0);
        __builtin_amdgcn_s_setprio(0);

        avh[0] = *(const bf16x8*)(ArdBase + offA0 + 2048);
        avh[1] = *(const bf16x8*)(ArdBase + offA0 + 3072);

        __builtin_amdgcn_s_setprio(1);
#pragma unroll
        for (int m = 0; m < 2; ++m)
#pragma unroll
            for (int n = 0; n < 4; ++n)
                acc[2 + m][n] = __builtin_amdgcn_mfma_f32_16x16x32_bf16(avh[m], bv[n], acc[2 + m][n], 0, 0, 0);
        __builtin_amdgcn_s_setprio(0);

        // rotate buffers
        int ta = offA0; offA0 = offA1; offA1 = offA2; offA2 = ta;
        int tb = offB0; offB0 = offB1; offB1 = offB2; offB2 = tb;
    }

    // epilogue: bias + activation + store
    const int gate = n0 >> 10;
    const float* bias = (gate == 0) ? bf_ : (gate == 1) ? bi_ : (gate == 2) ? big_ : bog_;
    T* Gg = G + (size_t)gate * GATE_ELEMS;
    const int ebase = (n0 & 1023) + wn * 64;
    const int rowb0 = m0 + wm * 64;
    float bvv[4];
#pragma unroll
    for (int nf = 0; nf < 4; ++nf) bvv[nf] = bias[ebase + nf * 16 + l15];
#pragma unroll
    for (int mf = 0; mf < 4; ++mf) {
        int rowb = rowb0 + mf * 16 + l4 * 4;
#pragma unroll
        for (int r = 0; r < 4; ++r) {
            size_t rowoff = (size_t)(rowb + r) * DIMD;
#pragma unroll
            for (int nf = 0; nf < 4; ++nf) {
                float pre = acc[mf][nf][r] + bvv[nf];
                float v = (gate == 1) ? (2.f * fsig(2.f * pre) - 1.f) : fsig(pre);
                gst(Gg, rowoff + ebase + nf * 16 + l15, v);
            }
        }
    }
}

// ---------------- scan phase 1: per-chunk affine aggregates ----------------
template <typename T>
__global__ void scan_phase1(const T* __restrict__ F, const T* __restrict__ TI,
                            const T* __restrict__ SG,
                            float* __restrict__ Aagg, float* __restrict__ Bagg) {
    const int d = blockIdx.x * blockDim.x + threadIdx.x;  // 0..1023
    const int c = blockIdx.y, b = blockIdx.z;
    size_t base = ((size_t)b * LSEQ + (size_t)c * CHUNKLEN) * DIMD + d;
    float A = 1.f, Bv = 0.f;
#pragma unroll 8
    for (int t = 0; t < CHUNKLEN; ++t) {
        size_t off = base + (size_t)t * DIMD;
        float f = gld(F, off);
        float i = gld(TI, off) * gld(SG, off);
        A *= f;
        Bv = __builtin_fmaf(f, Bv, i);
    }
    size_t o = ((size_t)b * NCHUNK + c) * DIMD + d;
    Aagg[o] = A;
    Bagg[o] = Bv;
}

// ---------------- scan phase 2: sequential scan over chunk aggregates ----------------
__global__ void scan_phase2(const float* __restrict__ Aagg, const float* __restrict__ Bagg,
                            const float* __restrict__ hidden,
                            float* __restrict__ Hstart, float* __restrict__ out_h) {
    int idx = blockIdx.x * blockDim.x + threadIdx.x;  // 0..4095
    int b = idx >> 10, d = idx & 1023;
    float h = hidden[b * 1024 + d];
    for (int c = 0; c < NCHUNK; ++c) {
        size_t o = ((size_t)b * NCHUNK + c) * DIMD + d;
        Hstart[o] = h;
        h = __builtin_fmaf(Aagg[o], h, Bagg[o]);
    }
    out_h[b * 1024 + d] = h;
}

// ---------------- scan phase 3: replay chunk with prefix, write y ----------------
template <typename T>
__global__ void scan_phase3(const T* __restrict__ F, const T* __restrict__ TI,
                            const T* __restrict__ SG, const T* __restrict__ OG,
                            const float* __restrict__ Hstart, float* __restrict__ y) {
    const int d = blockIdx.x * blockDim.x + threadIdx.x;
    const int c = blockIdx.y, b = blockIdx.z;
    float h = Hstart[((size_t)b * NCHUNK + c) * DIMD + d];
    size_t base = ((size_t)b * LSEQ + (size_t)c * CHUNKLEN) * DIMD + d;
#pragma unroll 4
    for (int t = 0; t < CHUNKLEN; ++t) {
        size_t off = base + (size_t)t * DIMD;
        float f = gld(F, off);
        float i = gld(TI, off) * gld(SG, off);
        h = __builtin_fmaf(f, h, i);
        y[off] = tanhf(h) * gld(OG, off);
    }
}

// ---------------- launch ----------------
extern "C" void kernel_launch(void* const* d_in, const int* in_sizes, int n_in,
                              void* d_out, int out_size, void* d_ws, size_t ws_size,
                              hipStream_t stream) {
    const float* x      = (const float*)d_in[0];
    const float* hidden = (const float*)d_in[1];
    const float* Wf  = (const float*)d_in[2];
    const float* bf_ = (const float*)d_in[3];
    const float* Wi  = (const float*)d_in[4];
    const float* bi_ = (const float*)d_in[5];
    const float* Wig = (const float*)d_in[6];
    const float* big_= (const float*)d_in[7];
    const float* Wog = (const float*)d_in[8];
    const float* bog_= (const float*)d_in[9];

    char* ws = (char*)d_ws;
    unsigned short* Xb   = (unsigned short*)(ws);            // 33,554,432 B
    unsigned short* Wcat = (unsigned short*)(ws + 33554432); //  8,388,608 B
    // gates start at 41,943,040

    float* y     = (float*)d_out;                 // [4][4096][1024]
    float* out_h = y + GATE_ELEMS;                // [4][1024]

    // casts
    cast_f32_to_bf16<<<MTOT * DIMD / 8 / 256, 256, 0, stream>>>(x, Xb, MTOT * DIMD);
    cast_f32_to_bf16<<<DIMD * DIMD / 8 / 256, 256, 0, stream>>>(Wf,  Wcat + 0 * DIMD * DIMD, DIMD * DIMD);
    cast_f32_to_bf16<<<DIMD * DIMD / 8 / 256, 256, 0, stream>>>(Wi,  Wcat + 1 * DIMD * DIMD, DIMD * DIMD);
    cast_f32_to_bf16<<<DIMD * DIMD / 8 / 256, 256, 0, stream>>>(Wig, Wcat + 2 * DIMD * DIMD, DIMD * DIMD);
    cast_f32_to_bf16<<<DIMD * DIMD / 8 / 256, 256, 0, stream>>>(Wog, Wcat + 3 * DIMD * DIMD, DIMD * DIMD);

    const int GRID = (MTOT / 128) * (4096 / 256);   // 2048
    const size_t FP32_WS_NEED = 33554432ull + 8388608ull + GATE_ELEMS * 4 * 4 + 3ull * 1048576ull;
    if (ws_size >= FP32_WS_NEED) {
        // -------- fp32-gate path --------
        float* G      = (float*)(ws + 41943040);
        float* Aagg   = (float*)(ws + 310378496);
        float* Bagg   = (float*)(ws + 311427072);
        float* Hstart = (float*)(ws + 312475648);
        gemm_gates_s<float><<<GRID, 512, 0, stream>>>(Xb, Wcat, bf_, bi_, big_, bog_, G);
        const float* Fg  = G;
        const float* TIg = G + 1 * GATE_ELEMS;
        const float* SGg = G + 2 * GATE_ELEMS;
        const float* OGg = G + 3 * GATE_ELEMS;
        scan_phase1<float><<<dim3(DIMD / 256, NCHUNK, BATCH), 256, 0, stream>>>(Fg, TIg, SGg, Aagg, Bagg);
        scan_phase2<<<BATCH * DIMD / 256, 256, 0, stream>>>(Aagg, Bagg, hidden, Hstart, out_h);
        scan_phase3<float><<<dim3(DIMD / 256, NCHUNK, BATCH), 256, 0, stream>>>(Fg, TIg, SGg, OGg, Hstart, y);
    } else {
        // -------- bf16-gate path (ws need: 179,306,496 B = 171 MiB) --------
        unsigned short* G = (unsigned short*)(ws + 41943040);
        float* Aagg   = (float*)(ws + 176160768);
        float* Bagg   = (float*)(ws + 177209344);
        float* Hstart = (float*)(ws + 178257920);
        gemm_gates_s<unsigned short><<<GRID, 512, 0, stream>>>(Xb, Wcat, bf_, bi_, big_, bog_, G);
        const unsigned short* Fg  = G;
        const unsigned short* TIg = G + 1 * GATE_ELEMS;
        const unsigned short* SGg = G + 2 * GATE_ELEMS;
        const unsigned short* OGg = G + 3 * GATE_ELEMS;
        scan_phase1<unsigned short><<<dim3(DIMD / 256, NCHUNK, BATCH), 256, 0, stream>>>(Fg, TIg, SGg, Aagg, Bagg);
        scan_phase2<<<BATCH * DIMD / 256, 256, 0, stream>>>(Aagg, Bagg, hidden, Hstart, out_h);
        scan_phase3<unsigned short><<<dim3(DIMD / 256, NCHUNK, BATCH), 256, 0, stream>>>(Fg, TIg, SGg, OGg, Hstart, y);
    }
}

// Round 10
// 240.370 us; speedup vs baseline: 1.0718x; 1.0423x over previous
//
#include <hip/hip_runtime.h>
#include <hip/hip_bf16.h>
#include <cstdint>
#include <cstddef>

#define DIMD 1024
#define LSEQ 4096
#define BATCH 4
#define MTOT (BATCH*LSEQ)          // 16384
#define NCHUNK 64
#define CHUNKLEN 64                // NCHUNK*CHUNKLEN == LSEQ
#define GATE_ELEMS ((size_t)MTOT*DIMD)
#define NTILE_K 32                 // 1024 / 32  (BK=32)

typedef __bf16 bf16x8 __attribute__((ext_vector_type(8)));
typedef float f32x4 __attribute__((ext_vector_type(4)));

__device__ __forceinline__ unsigned short f2bf(float f) {
    union { float f; uint32_t u; } v; v.f = f;
    uint32_t r = v.u + 0x7fffu + ((v.u >> 16) & 1u);   // RNE
    return (unsigned short)(r >> 16);
}
__device__ __forceinline__ float bits2f(unsigned short b) {
    union { uint32_t u; float f; } v; v.u = ((uint32_t)b) << 16; return v.f;
}
__device__ __forceinline__ float gld(const float* p, size_t o) { return p[o]; }
__device__ __forceinline__ float gld(const unsigned short* p, size_t o) { return bits2f(p[o]); }
__device__ __forceinline__ void  gst(float* p, size_t o, float v) { p[o] = v; }
__device__ __forceinline__ void  gst(unsigned short* p, size_t o, float v) { p[o] = f2bf(v); }

__device__ __forceinline__ float fsig(float x) {
    return __builtin_amdgcn_rcpf(1.f + __expf(-x));
}

// ---------------- fused cast fp32 -> bf16 (x + 4 weights, one launch) ----------------
__global__ void cast_all(const float* __restrict__ x,
                         const float* __restrict__ Wf, const float* __restrict__ Wi,
                         const float* __restrict__ Wig, const float* __restrict__ Wog,
                         unsigned short* __restrict__ Xb, unsigned short* __restrict__ Wcat) {
    int b = blockIdx.x;
    const float* src; unsigned short* dst; int lb;
    if (b < 8192) { src = x; dst = Xb; lb = b; }
    else {
        int w = (b - 8192) >> 9;             // 0..3 (512 blocks each)
        lb = (b - 8192) & 511;
        src = (w == 0) ? Wf : (w == 1) ? Wi : (w == 2) ? Wig : Wog;
        dst = Wcat + (size_t)w * DIMD * DIMD;
    }
    int i = (lb * 256 + threadIdx.x) * 8;
    float4 a = *(const float4*)(src + i);
    float4 c = *(const float4*)(src + i + 4);
    uint4 o;
    o.x = (uint32_t)f2bf(a.x) | ((uint32_t)f2bf(a.y) << 16);
    o.y = (uint32_t)f2bf(a.z) | ((uint32_t)f2bf(a.w) << 16);
    o.z = (uint32_t)f2bf(c.x) | ((uint32_t)f2bf(c.y) << 16);
    o.w = (uint32_t)f2bf(c.z) | ((uint32_t)f2bf(c.w) << 16);
    *(uint4*)(dst + i) = o;
}

// ---------------- 128x256-tile, BK=32, 3-buffer, 2 blocks/CU 4-gate GEMM ----------------
// Per-wave 64x64 (acc in AGPRs) -> 2 resident blocks (m114 inter-block overlap).
// 3 LDS buffers (72 KiB): stage(t+2) never WARs reads(t).
// Sync per tile: vmcnt(asm,"memory") -> s_barrier -> sched_barrier(0) -> stage|reads|MFMA.
// Swizzle (R10 fix): XOR term = (row>>1)&3 (not row&3). 64B rows give bank-slot
// (row&1, (row>>1)&3): bijective per quarter-wave -> exactly 2 lanes/bank = free.
// Lane-constant across fragments since wm*64/wn*64/mf*16/nf*16 are all multiples of 8.
template <typename T>
__global__ __launch_bounds__(512, 4) void gemm_gates_s(
    const unsigned short* __restrict__ Xb,    // [16384][1024] bf16 bits
    const unsigned short* __restrict__ Wcat,  // [4096][1024]  bf16 bits
    const float* __restrict__ bf_, const float* __restrict__ bi_,
    const float* __restrict__ big_, const float* __restrict__ bog_,
    T* __restrict__ G)                        // [4][16384][1024]
{
    __shared__ __align__(16) char lds[73728];   // A: 3x8KB @0 ; B: 3x16KB @24576
    char* ldsA = lds;
    char* ldsB = lds + 24576;

    const int tid = threadIdx.x;
    const int wave = tid >> 6, lane = tid & 63;
    const int wm = wave >> 2, wn = wave & 3;       // 2 x 4 wave grid
    const int l15 = lane & 15, l4 = lane >> 4;

    // T1: bijective XCD swizzle (2048 blocks, %8==0), 2 nt-slabs per XCD
    const int wg = blockIdx.x;
    const int swz = (wg & 7) * 256 + (wg >> 3);
    const int mt = swz & 127, nt = swz >> 7;
    const int m0 = mt * 128, n0 = nt * 256;

    // ---- swizzled LDS read bases (row=64B, col-group XOR ((row>>1)&3)) ----
    const int rsw = (l4 ^ ((l15 >> 1) & 3)) << 4;
    const char* ArdBase = ldsA + (wm * 64 + l15) * 64 + rsw;   // + m*1024 + offA
    const char* BrdBase = ldsB + (wn * 64 + l15) * 64 + rsw;   // + n*1024 + offB

    // ---- per-thread stage source bases (inverse swizzle on global col) ----
    const int srow = tid >> 2;                           // 0..127
    const int scg  = ((tid & 3) ^ ((srow >> 1) & 3)) * 8;  // col-group elem offset
    const unsigned short* pAsrc  = Xb   + (size_t)(m0 + srow) * DIMD + scg;
    const unsigned short* pBsrc0 = Wcat + (size_t)(n0 + srow) * DIMD + scg;
    const unsigned short* pBsrc1 = Wcat + (size_t)(n0 + 128 + srow) * DIMD + scg;

    auto stage3 = [&](int k0, int offA, int offB) {
        __builtin_amdgcn_global_load_lds(
            (const __attribute__((address_space(1))) uint32_t*)(pAsrc + k0),
            (__attribute__((address_space(3))) uint32_t*)(ldsA + offA + (wave << 10)), 16, 0, 0);
        __builtin_amdgcn_global_load_lds(
            (const __attribute__((address_space(1))) uint32_t*)(pBsrc0 + k0),
            (__attribute__((address_space(3))) uint32_t*)(ldsB + offB + (wave << 10)), 16, 0, 0);
        __builtin_amdgcn_global_load_lds(
            (const __attribute__((address_space(1))) uint32_t*)(pBsrc1 + k0),
            (__attribute__((address_space(3))) uint32_t*)(ldsB + offB + 8192 + (wave << 10)), 16, 0, 0);
    };

    f32x4 acc[4][4];
#pragma unroll
    for (int m = 0; m < 4; ++m)
#pragma unroll
        for (int n = 0; n < 4; ++n) acc[m][n] = (f32x4)0.f;

    // prologue: stage tiles 0 and 1
    stage3(0, 0, 0);
    stage3(32, 8192, 16384);

    int offA0 = 0, offA1 = 8192, offA2 = 16384;        // read / next / stage slots
    int offB0 = 0, offB1 = 16384, offB2 = 32768;       // (relative to ldsB)
#pragma unroll 1
    for (int t = 0; t < NTILE_K; ++t) {
        if (t <= NTILE_K - 2) asm volatile("s_waitcnt vmcnt(3)" ::: "memory");
        else                  asm volatile("s_waitcnt vmcnt(0)" ::: "memory");
        __builtin_amdgcn_s_barrier();          // all waves' tile-t loads landed
        __builtin_amdgcn_sched_barrier(0);     // no read/stage hoist above barrier

        if (t + 2 < NTILE_K) stage3((t + 2) * 32, offA2, offB2);

        bf16x8 bv[4], avl[2], avh[2];
#pragma unroll
        for (int n = 0; n < 4; ++n)
            bv[n] = *(const bf16x8*)(BrdBase + offB0 + n * 1024);
        avl[0] = *(const bf16x8*)(ArdBase + offA0);
        avl[1] = *(const bf16x8*)(ArdBase + offA0 + 1024);

        __builtin_amdgcn_s_setprio(1);
#pragma unroll
        for (int m = 0; m < 2; ++m)
#pragma unroll
            for (int n = 0; n < 4; ++n)
                acc[m][n] = __builtin_amdgcn_mfma_f32_16x16x32_bf16(avl[m], bv[n], acc[m][n], 0, 0, 0);
        __builtin_amdgcn_s_setprio(0);

        avh[0] = *(const bf16x8*)(ArdBase + offA0 + 2048);
        avh[1] = *(const bf16x8*)(ArdBase + offA0 + 3072);

        __builtin_amdgcn_s_setprio(1);
#pragma unroll
        for (int m = 0; m < 2; ++m)
#pragma unroll
            for (int n = 0; n < 4; ++n)
                acc[2 + m][n] = __builtin_amdgcn_mfma_f32_16x16x32_bf16(avh[m], bv[n], acc[2 + m][n], 0, 0, 0);
        __builtin_amdgcn_s_setprio(0);

        // rotate buffers
        int ta = offA0; offA0 = offA1; offA1 = offA2; offA2 = ta;
        int tb = offB0; offB0 = offB1; offB1 = offB2; offB2 = tb;
    }

    // epilogue: bias + activation + store
    const int gate = n0 >> 10;
    const float* bias = (gate == 0) ? bf_ : (gate == 1) ? bi_ : (gate == 2) ? big_ : bog_;
    T* Gg = G + (size_t)gate * GATE_ELEMS;
    const int ebase = (n0 & 1023) + wn * 64;
    const int rowb0 = m0 + wm * 64;
    float bvv[4];
#pragma unroll
    for (int nf = 0; nf < 4; ++nf) bvv[nf] = bias[ebase + nf * 16 + l15];
#pragma unroll
    for (int mf = 0; mf < 4; ++mf) {
        int rowb = rowb0 + mf * 16 + l4 * 4;
#pragma unroll
        for (int r = 0; r < 4; ++r) {
            size_t rowoff = (size_t)(rowb + r) * DIMD;
#pragma unroll
            for (int nf = 0; nf < 4; ++nf) {
                float pre = acc[mf][nf][r] + bvv[nf];
                float v = (gate == 1) ? (2.f * fsig(2.f * pre) - 1.f) : fsig(pre);
                gst(Gg, rowoff + ebase + nf * 16 + l15, v);
            }
        }
    }
}

// ---------------- scan phase 1: per-chunk affine aggregates ----------------
template <typename T>
__global__ void scan_phase1(const T* __restrict__ F, const T* __restrict__ TI,
                            const T* __restrict__ SG,
                            float* __restrict__ Aagg, float* __restrict__ Bagg) {
    const int d = blockIdx.x * blockDim.x + threadIdx.x;  // 0..1023
    const int c = blockIdx.y, b = blockIdx.z;
    size_t base = ((size_t)b * LSEQ + (size_t)c * CHUNKLEN) * DIMD + d;
    float A = 1.f, Bv = 0.f;
#pragma unroll 8
    for (int t = 0; t < CHUNKLEN; ++t) {
        size_t off = base + (size_t)t * DIMD;
        float f = gld(F, off);
        float i = gld(TI, off) * gld(SG, off);
        A *= f;
        Bv = __builtin_fmaf(f, Bv, i);
    }
    size_t o = ((size_t)b * NCHUNK + c) * DIMD + d;
    Aagg[o] = A;
    Bagg[o] = Bv;
}

// ---------------- scan phase 2: sequential scan over chunk aggregates ----------------
__global__ void scan_phase2(const float* __restrict__ Aagg, const float* __restrict__ Bagg,
                            const float* __restrict__ hidden,
                            float* __restrict__ Hstart, float* __restrict__ out_h) {
    int idx = blockIdx.x * blockDim.x + threadIdx.x;  // 0..4095
    int b = idx >> 10, d = idx & 1023;
    float h = hidden[b * 1024 + d];
    for (int c = 0; c < NCHUNK; ++c) {
        size_t o = ((size_t)b * NCHUNK + c) * DIMD + d;
        Hstart[o] = h;
        h = __builtin_fmaf(Aagg[o], h, Bagg[o]);
    }
    out_h[b * 1024 + d] = h;
}

// ---------------- scan phase 3: replay chunk with prefix, write y ----------------
template <typename T>
__global__ void scan_phase3(const T* __restrict__ F, const T* __restrict__ TI,
                            const T* __restrict__ SG, const T* __restrict__ OG,
                            const float* __restrict__ Hstart, float* __restrict__ y) {
    const int d = blockIdx.x * blockDim.x + threadIdx.x;
    const int c = blockIdx.y, b = blockIdx.z;
    float h = Hstart[((size_t)b * NCHUNK + c) * DIMD + d];
    size_t base = ((size_t)b * LSEQ + (size_t)c * CHUNKLEN) * DIMD + d;
#pragma unroll 4
    for (int t = 0; t < CHUNKLEN; ++t) {
        size_t off = base + (size_t)t * DIMD;
        float f = gld(F, off);
        float i = gld(TI, off) * gld(SG, off);
        h = __builtin_fmaf(f, h, i);
        y[off] = tanhf(h) * gld(OG, off);
    }
}

// ---------------- launch ----------------
extern "C" void kernel_launch(void* const* d_in, const int* in_sizes, int n_in,
                              void* d_out, int out_size, void* d_ws, size_t ws_size,
                              hipStream_t stream) {
    const float* x      = (const float*)d_in[0];
    const float* hidden = (const float*)d_in[1];
    const float* Wf  = (const float*)d_in[2];
    const float* bf_ = (const float*)d_in[3];
    const float* Wi  = (const float*)d_in[4];
    const float* bi_ = (const float*)d_in[5];
    const float* Wig = (const float*)d_in[6];
    const float* big_= (const float*)d_in[7];
    const float* Wog = (const float*)d_in[8];
    const float* bog_= (const float*)d_in[9];

    char* ws = (char*)d_ws;
    unsigned short* Xb   = (unsigned short*)(ws);            // 33,554,432 B
    unsigned short* Wcat = (unsigned short*)(ws + 33554432); //  8,388,608 B
    // gates start at 41,943,040

    float* y     = (float*)d_out;                 // [4][4096][1024]
    float* out_h = y + GATE_ELEMS;                // [4][1024]

    // fused casts (x: 8192 blocks, weights: 4 x 512 blocks)
    cast_all<<<10240, 256, 0, stream>>>(x, Wf, Wi, Wig, Wog, Xb, Wcat);

    const int GRID = (MTOT / 128) * (4096 / 256);   // 2048
    const size_t FP32_WS_NEED = 33554432ull + 8388608ull + GATE_ELEMS * 4 * 4 + 3ull * 1048576ull;
    if (ws_size >= FP32_WS_NEED) {
        // -------- fp32-gate path --------
        float* G      = (float*)(ws + 41943040);
        float* Aagg   = (float*)(ws + 310378496);
        float* Bagg   = (float*)(ws + 311427072);
        float* Hstart = (float*)(ws + 312475648);
        gemm_gates_s<float><<<GRID, 512, 0, stream>>>(Xb, Wcat, bf_, bi_, big_, bog_, G);
        const float* Fg  = G;
        const float* TIg = G + 1 * GATE_ELEMS;
        const float* SGg = G + 2 * GATE_ELEMS;
        const float* OGg = G + 3 * GATE_ELEMS;
        scan_phase1<float><<<dim3(DIMD / 256, NCHUNK, BATCH), 256, 0, stream>>>(Fg, TIg, SGg, Aagg, Bagg);
        scan_phase2<<<BATCH * DIMD / 256, 256, 0, stream>>>(Aagg, Bagg, hidden, Hstart, out_h);
        scan_phase3<float><<<dim3(DIMD / 256, NCHUNK, BATCH), 256, 0, stream>>>(Fg, TIg, SGg, OGg, Hstart, y);
    } else {
        // -------- bf16-gate path (ws need: 179,306,496 B = 171 MiB) --------
        unsigned short* G = (unsigned short*)(ws + 41943040);
        float* Aagg   = (float*)(ws + 176160768);
        float* Bagg   = (float*)(ws + 177209344);
        float* Hstart = (float*)(ws + 178257920);
        gemm_gates_s<unsigned short><<<GRID, 512, 0, stream>>>(Xb, Wcat, bf_, bi_, big_, bog_, G);
        const unsigned short* Fg  = G;
        const unsigned short* TIg = G + 1 * GATE_ELEMS;
        const unsigned short* SGg = G + 2 * GATE_ELEMS;
        const unsigned short* OGg = G + 3 * GATE_ELEMS;
        scan_phase1<unsigned short><<<dim3(DIMD / 256, NCHUNK, BATCH), 256, 0, stream>>>(Fg, TIg, SGg, Aagg, Bagg);
        scan_phase2<<<BATCH * DIMD / 256, 256, 0, stream>>>(Aagg, Bagg, hidden, Hstart, out_h);
        scan_phase3<unsigned short><<<dim3(DIMD / 256, NCHUNK, BATCH), 256, 0, stream>>>(Fg, TIg, SGg, OGg, Hstart, y);
    }
}

// Round 11
// 226.091 us; speedup vs baseline: 1.1395x; 1.0632x over previous
//
#include <hip/hip_runtime.h>
#include <hip/hip_bf16.h>
#include <cstdint>
#include <cstddef>

#define DIMD 1024
#define LSEQ 4096
#define BATCH 4
#define MTOT (BATCH*LSEQ)          // 16384
#define NCHUNK 64
#define CHUNKLEN 64
#define GATE_ELEMS ((size_t)MTOT*DIMD)
#define NTILE_K 32                 // 1024 / 32  (BK=32)

typedef __bf16 bf16x8 __attribute__((ext_vector_type(8)));
typedef float f32x4 __attribute__((ext_vector_type(4)));

__device__ __forceinline__ unsigned short f2bf(float f) {
    union { float f; uint32_t u; } v; v.f = f;
    uint32_t r = v.u + 0x7fffu + ((v.u >> 16) & 1u);   // RNE
    return (unsigned short)(r >> 16);
}
__device__ __forceinline__ float bits2f(unsigned short b) {
    union { uint32_t u; float f; } v; v.u = ((uint32_t)b) << 16; return v.f;
}
__device__ __forceinline__ float fsig(float x) {
    return __builtin_amdgcn_rcpf(1.f + __expf(-x));
}
__device__ __forceinline__ float ftanh(float x) {
    return 2.f * fsig(2.f * x) - 1.f;
}

// ---------------- fused cast fp32 -> bf16 (x + 4 weights, one launch) ----------------
__global__ void cast_all(const float* __restrict__ x,
                         const float* __restrict__ Wf, const float* __restrict__ Wi,
                         const float* __restrict__ Wig, const float* __restrict__ Wog,
                         unsigned short* __restrict__ Xb, unsigned short* __restrict__ Wcat) {
    int b = blockIdx.x;
    const float* src; unsigned short* dst; int lb;
    if (b < 8192) { src = x; dst = Xb; lb = b; }
    else {
        int w = (b - 8192) >> 9;             // 0..3 (512 blocks each)
        lb = (b - 8192) & 511;
        src = (w == 0) ? Wf : (w == 1) ? Wi : (w == 2) ? Wig : Wog;
        dst = Wcat + (size_t)w * DIMD * DIMD;
    }
    int i = (lb * 256 + threadIdx.x) * 8;
    float4 a = *(const float4*)(src + i);
    float4 c = *(const float4*)(src + i + 4);
    uint4 o;
    o.x = (uint32_t)f2bf(a.x) | ((uint32_t)f2bf(a.y) << 16);
    o.y = (uint32_t)f2bf(a.z) | ((uint32_t)f2bf(a.w) << 16);
    o.z = (uint32_t)f2bf(c.x) | ((uint32_t)f2bf(c.y) << 16);
    o.w = (uint32_t)f2bf(c.z) | ((uint32_t)f2bf(c.w) << 16);
    *(uint4*)(dst + i) = o;
}

// ---------------- gate-fused 128x(64e x 4 gates) GEMM + scan-phase1 fusion ----------------
// Block computes, for rows [m0,m0+128) and e-cols [e0,e0+64), ALL FOUR gates
// (wave wn = gate, wm = row half). Inner loop identical to R10 (BK=32, 3-buf,
// 2 blocks/CU, swizzle XOR (row>>1)&3, vmcnt->barrier->sched_barrier).
// Epilogue: activation in place; f/sg cross to LDS; wn==1 stores i=ti*sg and
// computes per-chunk affine aggregates (A=prod f, B) in-register:
// t = mf*16 + l4*4 + r; r-loop -> ordered shfl_xor(16/32) butterfly over l4 ->
// mf-compose. Wave's 64 rows == exactly one scan chunk (gc = m0/64 + wm).
__global__ __launch_bounds__(512, 4) void gemm_gates_f(
    const unsigned short* __restrict__ Xb,    // [16384][1024] bf16 bits
    const unsigned short* __restrict__ Wcat,  // [4][1024][1024] bf16 bits
    const float* __restrict__ bf_, const float* __restrict__ bi_,
    const float* __restrict__ big_, const float* __restrict__ bog_,
    unsigned short* __restrict__ F, unsigned short* __restrict__ I,
    unsigned short* __restrict__ OG,
    float* __restrict__ Aagg, float* __restrict__ Bagg)
{
    __shared__ __align__(16) char lds[73728];   // A: 3x8KB @0 ; B: 3x16KB @24576
    char* ldsA = lds;
    char* ldsB = lds + 24576;

    const int tid = threadIdx.x;
    const int wave = tid >> 6, lane = tid & 63;
    const int wm = wave >> 2, wn = wave & 3;       // wm: row half, wn: GATE
    const int l15 = lane & 15, l4 = lane >> 4;

    // T1: bijective XCD swizzle (2048 blocks, %8==0)
    const int wg = blockIdx.x;
    const int swz = (wg & 7) * 256 + (wg >> 3);
    const int mt = swz & 127, et = swz >> 7;       // mt 0..127, et 0..15
    const int m0 = mt * 128, e0 = et * 64;

    // ---- swizzled LDS read bases ----
    const int rsw = (l4 ^ ((l15 >> 1) & 3)) << 4;
    const char* ArdBase = ldsA + (wm * 64 + l15) * 64 + rsw;
    const char* BrdBase = ldsB + (wn * 64 + l15) * 64 + rsw;

    // ---- per-thread stage source bases (inverse swizzle on global col) ----
    const int srow = tid >> 2;                             // 0..127
    const int scg  = ((tid & 3) ^ ((srow >> 1) & 3)) * 8;
    const unsigned short* pAsrc = Xb + (size_t)(m0 + srow) * DIMD + scg;
    // B LDS rows 0..127 = gates 0,1 ; 128..255 = gates 2,3 (64 e-cols each)
    const unsigned short* pBsrc0 = Wcat + (size_t)((srow >> 6) * 1024 + e0 + (srow & 63)) * DIMD + scg;
    const unsigned short* pBsrc1 = Wcat + (size_t)((2 + (srow >> 6)) * 1024 + e0 + (srow & 63)) * DIMD + scg;

    auto stage3 = [&](int k0, int offA, int offB) {
        __builtin_amdgcn_global_load_lds(
            (const __attribute__((address_space(1))) uint32_t*)(pAsrc + k0),
            (__attribute__((address_space(3))) uint32_t*)(ldsA + offA + (wave << 10)), 16, 0, 0);
        __builtin_amdgcn_global_load_lds(
            (const __attribute__((address_space(1))) uint32_t*)(pBsrc0 + k0),
            (__attribute__((address_space(3))) uint32_t*)(ldsB + offB + (wave << 10)), 16, 0, 0);
        __builtin_amdgcn_global_load_lds(
            (const __attribute__((address_space(1))) uint32_t*)(pBsrc1 + k0),
            (__attribute__((address_space(3))) uint32_t*)(ldsB + offB + 8192 + (wave << 10)), 16, 0, 0);
    };

    f32x4 acc[4][4];
#pragma unroll
    for (int m = 0; m < 4; ++m)
#pragma unroll
        for (int n = 0; n < 4; ++n) acc[m][n] = (f32x4)0.f;

    // prologue: stage tiles 0 and 1
    stage3(0, 0, 0);
    stage3(32, 8192, 16384);

    int offA0 = 0, offA1 = 8192, offA2 = 16384;
    int offB0 = 0, offB1 = 16384, offB2 = 32768;
#pragma unroll 1
    for (int t = 0; t < NTILE_K; ++t) {
        if (t <= NTILE_K - 2) asm volatile("s_waitcnt vmcnt(3)" ::: "memory");
        else                  asm volatile("s_waitcnt vmcnt(0)" ::: "memory");
        __builtin_amdgcn_s_barrier();          // all waves' tile-t loads landed
        __builtin_amdgcn_sched_barrier(0);

        if (t + 2 < NTILE_K) stage3((t + 2) * 32, offA2, offB2);

        bf16x8 bv[4], avl[2], avh[2];
#pragma unroll
        for (int n = 0; n < 4; ++n)
            bv[n] = *(const bf16x8*)(BrdBase + offB0 + n * 1024);
        avl[0] = *(const bf16x8*)(ArdBase + offA0);
        avl[1] = *(const bf16x8*)(ArdBase + offA0 + 1024);

        __builtin_amdgcn_s_setprio(1);
#pragma unroll
        for (int m = 0; m < 2; ++m)
#pragma unroll
            for (int n = 0; n < 4; ++n)
                acc[m][n] = __builtin_amdgcn_mfma_f32_16x16x32_bf16(avl[m], bv[n], acc[m][n], 0, 0, 0);
        __builtin_amdgcn_s_setprio(0);

        avh[0] = *(const bf16x8*)(ArdBase + offA0 + 2048);
        avh[1] = *(const bf16x8*)(ArdBase + offA0 + 3072);

        __builtin_amdgcn_s_setprio(1);
#pragma unroll
        for (int m = 0; m < 2; ++m)
#pragma unroll
            for (int n = 0; n < 4; ++n)
                acc[2 + m][n] = __builtin_amdgcn_mfma_f32_16x16x32_bf16(avh[m], bv[n], acc[2 + m][n], 0, 0, 0);
        __builtin_amdgcn_s_setprio(0);

        int ta = offA0; offA0 = offA1; offA1 = offA2; offA2 = ta;
        int tb = offB0; offB0 = offB1; offB1 = offB2; offB2 = tb;
    }

    // ================= epilogue =================
    const float* biasg = (wn == 0) ? bf_ : (wn == 1) ? bi_ : (wn == 2) ? big_ : bog_;
    float bvv[4];
#pragma unroll
    for (int nf = 0; nf < 4; ++nf) bvv[nf] = biasg[e0 + nf * 16 + l15];

    // activation in place (wn==1 -> tanh, else sigmoid)
#pragma unroll
    for (int mf = 0; mf < 4; ++mf)
#pragma unroll
        for (int nf = 0; nf < 4; ++nf)
#pragma unroll
            for (int r = 0; r < 4; ++r) {
                float pre = acc[mf][nf][r] + bvv[nf];
                acc[mf][nf][r] = (wn == 1) ? ftanh(pre) : fsig(pre);
            }

    // cross-wave handoff: f (wn==0) and sg (wn==2) tiles -> LDS
    float* ldsF  = (float*)lds;              // [2][64][64] f32 = 32 KB
    float* ldsSG = (float*)(lds + 32768);    // [2][64][64] f32 = 32 KB
    __builtin_amdgcn_s_barrier();            // main-loop LDS fully consumed
    if (wn == 0 || wn == 2) {
        float* dstL = (wn == 0 ? ldsF : ldsSG) + wm * 4096;
#pragma unroll
        for (int mf = 0; mf < 4; ++mf)
#pragma unroll
            for (int nf = 0; nf < 4; ++nf)
#pragma unroll
                for (int r = 0; r < 4; ++r)
                    dstL[(mf * 16 + l4 * 4 + r) * 64 + nf * 16 + l15] = acc[mf][nf][r];
    }
    __builtin_amdgcn_s_barrier();

    const size_t rowbase = (size_t)(m0 + wm * 64) * DIMD + e0;
    if (wn == 0) {
        // store F
#pragma unroll
        for (int mf = 0; mf < 4; ++mf)
#pragma unroll
            for (int r = 0; r < 4; ++r) {
                size_t ro = rowbase + (size_t)(mf * 16 + l4 * 4 + r) * DIMD;
#pragma unroll
                for (int nf = 0; nf < 4; ++nf)
                    F[ro + nf * 16 + l15] = f2bf(acc[mf][nf][r]);
            }
    } else if (wn == 3) {
        // store OG
#pragma unroll
        for (int mf = 0; mf < 4; ++mf)
#pragma unroll
            for (int r = 0; r < 4; ++r) {
                size_t ro = rowbase + (size_t)(mf * 16 + l4 * 4 + r) * DIMD;
#pragma unroll
                for (int nf = 0; nf < 4; ++nf)
                    OG[ro + nf * 16 + l15] = f2bf(acc[mf][nf][r]);
            }
    } else if (wn == 1) {
        // store I = ti*sg; compute chunk aggregates (A = prod f, B)
        const float* fL  = ldsF  + wm * 4096;
        const float* sgL = ldsSG + wm * 4096;
        const int gc = (m0 >> 6) + wm;           // global chunk id (b*64+c)
#pragma unroll
        for (int nf = 0; nf < 4; ++nf) {
            float A = 1.f, Bv = 0.f;             // running compose over mf (ascending t)
#pragma unroll
            for (int mf = 0; mf < 4; ++mf) {
                float sA = 1.f, sB = 0.f;        // segment over r (4 consecutive t)
#pragma unroll
                for (int r = 0; r < 4; ++r) {
                    int row = mf * 16 + l4 * 4 + r;
                    int ecl = nf * 16 + l15;
                    float fv = fL[row * 64 + ecl];
                    float iv = acc[mf][nf][r] * sgL[row * 64 + ecl];
                    I[rowbase + (size_t)row * DIMD + ecl] = f2bf(iv);
                    sA = fv * sA;
                    sB = __builtin_fmaf(fv, sB, iv);
                }
                // ordered butterfly across l4 (lane^16 then lane^32)
#pragma unroll
                for (int s = 16; s <= 32; s <<= 1) {
                    float Ap = __shfl_xor(sA, s, 64);
                    float Bp = __shfl_xor(sB, s, 64);
                    bool later = (lane & s) != 0;
                    float aE = later ? Ap : sA, bE = later ? Bp : sB;
                    float aL = later ? sA : Ap, bL = later ? sB : Bp;
                    sA = aE * aL;
                    sB = __builtin_fmaf(aL, bE, bL);
                }
                // compose segment (later) onto running total
                Bv = __builtin_fmaf(sA, Bv, sB);
                A  = A * sA;
            }
            if (l4 == 0) {
                int e = e0 + nf * 16 + l15;
                Aagg[(size_t)gc * DIMD + e] = A;
                Bagg[(size_t)gc * DIMD + e] = Bv;
            }
        }
    }
    // wn==2: sg handed off via LDS; nothing global to store
}

// ---------------- scan phase 2: sequential scan over chunk aggregates ----------------
__global__ void scan_phase2(const float* __restrict__ Aagg, const float* __restrict__ Bagg,
                            const float* __restrict__ hidden,
                            float* __restrict__ Hstart, float* __restrict__ out_h) {
    int idx = blockIdx.x * blockDim.x + threadIdx.x;  // 0..4095
    int b = idx >> 10, d = idx & 1023;
    float h = hidden[b * 1024 + d];
    for (int c = 0; c < NCHUNK; ++c) {
        size_t o = ((size_t)b * NCHUNK + c) * DIMD + d;
        Hstart[o] = h;
        h = __builtin_fmaf(Aagg[o], h, Bagg[o]);
    }
    out_h[b * 1024 + d] = h;
}

// ---------------- scan phase 3: replay chunk with prefix, write y ----------------
__global__ void scan_phase3(const unsigned short* __restrict__ F,
                            const unsigned short* __restrict__ I,
                            const unsigned short* __restrict__ OG,
                            const float* __restrict__ Hstart, float* __restrict__ y) {
    const int d = blockIdx.x * blockDim.x + threadIdx.x;
    const int c = blockIdx.y, b = blockIdx.z;
    float h = Hstart[((size_t)b * NCHUNK + c) * DIMD + d];
    size_t base = ((size_t)b * LSEQ + (size_t)c * CHUNKLEN) * DIMD + d;
#pragma unroll 4
    for (int t = 0; t < CHUNKLEN; ++t) {
        size_t off = base + (size_t)t * DIMD;
        h = __builtin_fmaf(bits2f(F[off]), h, bits2f(I[off]));
        y[off] = ftanh(h) * bits2f(OG[off]);
    }
}

// ---------------- launch ----------------
extern "C" void kernel_launch(void* const* d_in, const int* in_sizes, int n_in,
                              void* d_out, int out_size, void* d_ws, size_t ws_size,
                              hipStream_t stream) {
    const float* x      = (const float*)d_in[0];
    const float* hidden = (const float*)d_in[1];
    const float* Wf  = (const float*)d_in[2];
    const float* bf_ = (const float*)d_in[3];
    const float* Wi  = (const float*)d_in[4];
    const float* bi_ = (const float*)d_in[5];
    const float* Wig = (const float*)d_in[6];
    const float* big_= (const float*)d_in[7];
    const float* Wog = (const float*)d_in[8];
    const float* bog_= (const float*)d_in[9];

    char* ws = (char*)d_ws;
    unsigned short* Xb   = (unsigned short*)(ws);             // 33,554,432 B
    unsigned short* Wcat = (unsigned short*)(ws + 33554432);  //  8,388,608 B
    unsigned short* F    = (unsigned short*)(ws + 41943040);  // 33,554,432 B
    unsigned short* I    = (unsigned short*)(ws + 75497472);  // 33,554,432 B
    unsigned short* OG   = (unsigned short*)(ws + 109051904); // 33,554,432 B
    float* Aagg   = (float*)(ws + 142606336);                 //  1,048,576 B
    float* Bagg   = (float*)(ws + 143654912);                 //  1,048,576 B
    float* Hstart = (float*)(ws + 144703488);                 //  1,048,576 B
    // total ws need: 145,752,064 B

    float* y     = (float*)d_out;                 // [4][4096][1024]
    float* out_h = y + GATE_ELEMS;                // [4][1024]

    // fused casts (x: 8192 blocks, weights: 4 x 512 blocks)
    cast_all<<<10240, 256, 0, stream>>>(x, Wf, Wi, Wig, Wog, Xb, Wcat);

    // gate-fused GEMM + activations + i-product + scan-phase1 aggregates
    gemm_gates_f<<<2048, 512, 0, stream>>>(Xb, Wcat, bf_, bi_, big_, bog_,
                                           F, I, OG, Aagg, Bagg);

    // chunk-prefix scan + replay
    scan_phase2<<<BATCH * DIMD / 256, 256, 0, stream>>>(Aagg, Bagg, hidden, Hstart, out_h);
    scan_phase3<<<dim3(DIMD / 256, NCHUNK, BATCH), 256, 0, stream>>>(F, I, OG, Hstart, y);
}